// Round 6
// baseline (247.796 us; speedup 1.0000x reference)
//
#include <hip/hip_runtime.h>
#include <hip/hip_bf16.h>

#define BB 8
#define NN 2048
#define FIN 128
#define FO 64
#define ALPHA 0.2f

typedef __attribute__((ext_vector_type(8))) short bf16x8;
typedef __attribute__((ext_vector_type(4))) float f32x4;
typedef __attribute__((ext_vector_type(4))) int i32x4;

typedef __attribute__((address_space(1))) const void gvoid;
typedef __attribute__((address_space(3))) void lvoid;

__device__ inline void gl_lds16(const void* g, void* l) {
    // async global->LDS DMA, 16B/lane; LDS dest = wave-uniform base + lane*16
    __builtin_amdgcn_global_load_lds((gvoid*)g, (lvoid*)l, 16, 0, 0);
}

__device__ inline short f2bf(float x) {
    unsigned u = __float_as_uint(x);
    u += 0x7fffu + ((u >> 16) & 1u);   // RNE
    return (short)(u >> 16);
}

// ---------------- Kernel A: Wh = h@W; whF in MFMA B-fragment layout ----------
// whF[b][jc][ot][L][8]: lane L holds Wh[b][j=jc*32+(L>>4)*8+jj][o=ot*16+(L&15)]
__global__ __launch_bounds__(256) void wh_kernel(
    const float* __restrict__ h, const float* __restrict__ W,
    const float* __restrict__ a, float* __restrict__ e1, float* __restrict__ e2,
    short* __restrict__ whF)
{
    __shared__ float hs[32][FIN];
    const int r0 = blockIdx.x * 32;
    const int t = threadIdx.x;
    const float4* hsrc = (const float4*)(h + (size_t)r0 * FIN);
    float4* hdst = (float4*)(&hs[0][0]);
#pragma unroll
    for (int k = 0; k < 4; k++) hdst[t + 256 * k] = hsrc[t + 256 * k];
    __syncthreads();

    const int o = t & 63;
    const int wv = t >> 6;
    float acc[8];
#pragma unroll
    for (int rr = 0; rr < 8; rr++) acc[rr] = 0.f;

    for (int f = 0; f < FIN; f += 4) {
        const float w0 = W[(f + 0) * FO + o];
        const float w1 = W[(f + 1) * FO + o];
        const float w2 = W[(f + 2) * FO + o];
        const float w3 = W[(f + 3) * FO + o];
#pragma unroll
        for (int rr = 0; rr < 8; rr++) {
            float4 hv = *(const float4*)&hs[wv * 8 + rr][f];
            acc[rr] = fmaf(hv.x, w0, acc[rr]);
            acc[rr] = fmaf(hv.y, w1, acc[rr]);
            acc[rr] = fmaf(hv.z, w2, acc[rr]);
            acc[rr] = fmaf(hv.w, w3, acc[rr]);
        }
    }

    const int b   = r0 / NN;
    const int ib0 = r0 - b * NN;
    const int ibb = ib0 + wv * 8;
    const int jc  = ibb >> 5;
    const int qq  = (ibb >> 3) & 3;
    const int ot  = o >> 4, mm = o & 15;
    const int L   = mm + qq * 16;
    bf16x8 frag;
#pragma unroll
    for (int rr = 0; rr < 8; rr++) frag[rr] = f2bf(acc[rr]);
    *(bf16x8*)(whF + ((((size_t)(b * 64 + jc) * 4 + ot) * 64 + L) * 8)) = frag;

    const float a1 = a[o], a2 = a[FO + o];
#pragma unroll
    for (int rr = 0; rr < 8; rr++) {
        float v1 = acc[rr] * a1, v2 = acc[rr] * a2;
#pragma unroll
        for (int msk = 32; msk >= 1; msk >>= 1) {
            v1 += __shfl_xor(v1, msk, 64);
            v2 += __shfl_xor(v2, msk, 64);
        }
        if (o == 0) { e1[r0 + wv * 8 + rr] = v1; e2[r0 + wv * 8 + rr] = v2; }
    }
}

// ---------------- Kernel A2: e2max per batch --------------------------------
__global__ __launch_bounds__(256) void e2max_kernel(
    const float* __restrict__ e2, float* __restrict__ e2max)
{
    const int b = blockIdx.x;
    const int t = threadIdx.x;
    float m = -1e30f;
    for (int j = t; j < NN; j += 256) m = fmaxf(m, e2[b * NN + j]);
#pragma unroll
    for (int k = 32; k >= 1; k >>= 1) m = fmaxf(m, __shfl_xor(m, k, 64));
    __shared__ float red[4];
    if ((t & 63) == 0) red[t >> 6] = m;
    __syncthreads();
    if (t == 0) e2max[b] = fmaxf(fmaxf(red[0], red[1]), fmaxf(red[2], red[3]));
}

// ---------------- Kernel A3: pack adj -> bitmask (134 MB -> 4.2 MB) ---------
// pk[row][c] u64: bit i of word c = (adj[row][c*64+i] > 0). Coalesced 256B/wave.
__global__ __launch_bounds__(256) void pack_kernel(
    const int* __restrict__ adj, unsigned long long* __restrict__ pk)
{
    const int t = threadIdx.x, wv = t >> 6, lane = t & 63;
    const size_t row0 = (size_t)blockIdx.x * 8;
#pragma unroll
    for (int rr = 0; rr < 8; rr++) {
        const size_t row = row0 + rr;
        const int* src = adj + row * NN + wv * 512;
#pragma unroll
        for (int c = 0; c < 8; c++) {
            unsigned long long mk = __ballot(src[c * 64 + lane] > 0);
            if (lane == 0) pk[row * 32 + wv * 8 + c] = mk;
        }
    }
}

// ---------------- Kernel B: bitmask fused attention -------------------------
// Block = (b, 32 rows = two 16-row A-tiles); wave w owns j-stripe [w*512,+512).
// adj bits (8.5 KB) + e2 staged in LDS ONCE before the K-loop; the loop's only
// VMEM is the whF fragment prefetch (compiler emits fine-grained vmcnt).
struct SMemS { unsigned pk[32][68]; float e2s[4][512]; };   // 8.7 KB + 8 KB
struct SMemC { float comb[4][2][16][64]; float lsum[4][2][16]; };
union SMemU { SMemS s; SMemC c; };

struct WFrag { bf16x8 f0, f1, f2, f3; };

#define WLOAD(dst, k) do { \
    const short* bfp = whFw + (size_t)(k) * 2048; \
    dst.f0 = *(const bf16x8*)(bfp); \
    dst.f1 = *(const bf16x8*)(bfp + 512); \
    dst.f2 = *(const bf16x8*)(bfp + 1024); \
    dst.f3 = *(const bf16x8*)(bfp + 1536); \
} while (0)

#define SCORE8(AU, D, E1C, NM2) do { \
    float pe[8]; \
    _Pragma("unroll") \
    for (int jj = 0; jj < 8; jj++) { \
        const float fb = (float)((D >> (q8 + jj)) & 1u); \
        const float ej = (jj < 4) ? ev0[jj] : ev1[jj - 4]; \
        const float s  = fmaf(ej, L2E, E1C); \
        const float lk = fmaxf(s, ALPHA * s); \
        pe[jj] = __builtin_amdgcn_exp2f(lk + fmaf(fb, 16000.f, NM2)); \
    } \
    _Pragma("unroll") \
    for (int jj = 0; jj < 4; jj++) \
        AU.u[jj] = __builtin_amdgcn_perm(__float_as_uint(pe[2 * jj + 1]), \
                                         __float_as_uint(pe[2 * jj]), 0x07060302u); \
} while (0)

#define STEPC(k, WF) do { \
    const unsigned d0 = lspk[m][w16 + (k)]; \
    const unsigned d1 = lspk[16 + m][w16 + (k)]; \
    f32x4 ev0 = *(const f32x4*)&le2[(k) * 32 + q * 8]; \
    f32x4 ev1 = *(const f32x4*)&le2[(k) * 32 + q * 8 + 4]; \
    union { unsigned u[4]; bf16x8 v; } au0, au1; \
    SCORE8(au0, d0, E1v0, negMi20); \
    SCORE8(au1, d1, E1v1, negMi21); \
    acc00 = __builtin_amdgcn_mfma_f32_16x16x32_bf16(au0.v, WF.f0, acc00, 0, 0, 0); \
    acc01 = __builtin_amdgcn_mfma_f32_16x16x32_bf16(au0.v, WF.f1, acc01, 0, 0, 0); \
    acc02 = __builtin_amdgcn_mfma_f32_16x16x32_bf16(au0.v, WF.f2, acc02, 0, 0, 0); \
    acc03 = __builtin_amdgcn_mfma_f32_16x16x32_bf16(au0.v, WF.f3, acc03, 0, 0, 0); \
    acc04 = __builtin_amdgcn_mfma_f32_16x16x32_bf16(au0.v, ones, acc04, 0, 0, 0); \
    acc10 = __builtin_amdgcn_mfma_f32_16x16x32_bf16(au1.v, WF.f0, acc10, 0, 0, 0); \
    acc11 = __builtin_amdgcn_mfma_f32_16x16x32_bf16(au1.v, WF.f1, acc11, 0, 0, 0); \
    acc12 = __builtin_amdgcn_mfma_f32_16x16x32_bf16(au1.v, WF.f2, acc12, 0, 0, 0); \
    acc13 = __builtin_amdgcn_mfma_f32_16x16x32_bf16(au1.v, WF.f3, acc13, 0, 0, 0); \
    acc14 = __builtin_amdgcn_mfma_f32_16x16x32_bf16(au1.v, ones, acc14, 0, 0, 0); \
} while (0)

__global__ __launch_bounds__(256) void attn_kernel(
    const unsigned long long* __restrict__ pkg, const float* __restrict__ e1,
    const float* __restrict__ e2, const float* __restrict__ e2max,
    const short* __restrict__ whF, float* __restrict__ out)
{
    __shared__ __align__(16) SMemU sm;
    const int t = threadIdx.x, w = t >> 6, lane = t & 63;
    const int m = lane & 15, q = lane >> 4;
    const int q8 = q * 8, w16 = w * 16;
    const int blk = blockIdx.x;
    const int b = blk >> 6, i0 = (blk & 63) * 32;

    const float L2E = 1.4426950408889634f;
    const float e2m = e2max[b];
    const float e1v0 = e1[b * NN + i0 + m];
    const float e1v1 = e1[b * NN + i0 + 16 + m];
    float mr0 = e1v0 + e2m; mr0 = mr0 > 0.f ? mr0 : ALPHA * mr0;
    float mr1 = e1v1 + e2m; mr1 = mr1 > 0.f ? mr1 : ALPHA * mr1;
    const float E1v0 = e1v0 * L2E, E1v1 = e1v1 * L2E;
    const float negMi20 = -(mr0 * L2E) - 16000.0f;   // +16000*bit restores -mr*L2E
    const float negMi21 = -(mr1 * L2E) - 16000.0f;

    // stage adj bits for this block's 32 rows: 8 KB contiguous -> padded LDS
    {
        const unsigned* pg = (const unsigned*)pkg + (size_t)(b * NN + i0) * 64;
        const int r = t >> 3, c = (t & 7) * 8;
        i32x4 v0 = *(const i32x4*)(pg + r * 64 + c);
        i32x4 v1 = *(const i32x4*)(pg + r * 64 + c + 4);
        *(i32x4*)&sm.s.pk[r][c] = v0;
        *(i32x4*)&sm.s.pk[r][c + 4] = v1;
    }
    float* le2 = sm.s.e2s[w];
    const float* e2src = e2 + b * NN + w * 512 + lane * 4;
    gl_lds16(e2src,       &le2[0]);
    gl_lds16(e2src + 256, &le2[256]);
    __syncthreads();                       // drains DMA (vmcnt(0) before barrier)

    const unsigned (*lspk)[68] = sm.s.pk;
    const short* whFw = whF + (size_t)b * (64 * 4 * 64 * 8)
                            + (size_t)(w * 16) * 2048 + lane * 8;

    f32x4 z = {0.f,0.f,0.f,0.f};
    f32x4 acc00 = z, acc01 = z, acc02 = z, acc03 = z, acc04 = z;
    f32x4 acc10 = z, acc11 = z, acc12 = z, acc13 = z, acc14 = z;
    bf16x8 ones;
#pragma unroll
    for (int jj = 0; jj < 8; jj++) ones[jj] = (short)0x3F80;   // bf16 1.0

    WFrag W0f, W1f;
    WLOAD(W0f, 0); WLOAD(W1f, 1);
#pragma unroll 1
    for (int k = 0; k < 12; k += 2) {
        WFrag Wa; WLOAD(Wa, k + 2); STEPC(k, W0f); W0f = Wa;
        WFrag Wb; WLOAD(Wb, k + 3); STEPC(k + 1, W1f); W1f = Wb;
    }
    { WFrag Wa; WLOAD(Wa, 14); STEPC(12, W0f); W0f = Wa; }
    { WFrag Wb; WLOAD(Wb, 15); STEPC(13, W1f); W1f = Wb; }
    STEPC(14, W0f);
    STEPC(15, W1f);

    __syncthreads();                       // staging LDS dead; reuse as comb
    if (m == 0) {
#pragma unroll
        for (int r = 0; r < 4; r++) {
            sm.c.lsum[w][0][q * 4 + r] = acc04[r];
            sm.c.lsum[w][1][q * 4 + r] = acc14[r];
        }
    }
#pragma unroll
    for (int ot = 0; ot < 4; ot++) {
        f32x4 a0 = (ot == 0) ? acc00 : (ot == 1) ? acc01 : (ot == 2) ? acc02 : acc03;
        f32x4 a1 = (ot == 0) ? acc10 : (ot == 1) ? acc11 : (ot == 2) ? acc12 : acc13;
#pragma unroll
        for (int reg = 0; reg < 4; reg++) {
            sm.c.comb[w][0][q * 4 + reg][ot * 16 + m] = a0[reg];
            sm.c.comb[w][1][q * 4 + reg][ot * 16 + m] = a1[reg];
        }
    }
    __syncthreads();

#pragma unroll
    for (int it = 0; it < 2; it++) {
        const int idx = t + it * 256;
        const int row = idx >> 4;
        const int tl = row >> 4, r16 = row & 15;
        const int c0 = (idx & 15) * 4;
        f32x4 sum = *(const f32x4*)&sm.c.comb[0][tl][r16][c0];
#pragma unroll
        for (int ww = 1; ww < 4; ww++) {
            f32x4 sv = *(const f32x4*)&sm.c.comb[ww][tl][r16][c0];
            sum.x += sv.x; sum.y += sv.y; sum.z += sv.z; sum.w += sv.w;
        }
        float l = sm.c.lsum[0][tl][r16] + sm.c.lsum[1][tl][r16]
                + sm.c.lsum[2][tl][r16] + sm.c.lsum[3][tl][r16];
        l = fmaxf(l, 1e-30f);
        const float rl = 1.f / l;
        f32x4 res;
        float vr[4] = { sum.x * rl, sum.y * rl, sum.z * rl, sum.w * rl };
#pragma unroll
        for (int kk = 0; kk < 4; kk++)
            res[kk] = vr[kk] > 0.f ? vr[kk] : (__expf(vr[kk]) - 1.f);
        *(f32x4*)&out[((size_t)(b * NN + i0 + row)) * FO + c0] = res;
    }
}

extern "C" void kernel_launch(void* const* d_in, const int* in_sizes, int n_in,
                              void* d_out, int out_size, void* d_ws, size_t ws_size,
                              hipStream_t stream) {
    const float* h   = (const float*)d_in[0];
    const int*   adj = (const int*)d_in[1];
    const float* W   = (const float*)d_in[2];
    const float* a   = (const float*)d_in[3];
    float* out = (float*)d_out;

    char* ws = (char*)d_ws;
    short* whF = (short*)ws;                                   // 2 MB
    size_t off = (size_t)BB * 64 * 4 * 64 * 8 * sizeof(short);
    float* e1  = (float*)(ws + off);  off += (size_t)BB * NN * 4;
    float* e2  = (float*)(ws + off);  off += (size_t)BB * NN * 4;
    float* e2m = (float*)(ws + off);  off += 256;
    unsigned long long* pk = (unsigned long long*)(ws + off);  // 4.2 MB

    wh_kernel<<<(BB * NN) / 32, 256, 0, stream>>>(h, W, a, e1, e2, whF);
    e2max_kernel<<<BB, 256, 0, stream>>>(e2, e2m);
    pack_kernel<<<(BB * NN) / 8, 256, 0, stream>>>(adj, pk);
    attn_kernel<<<BB * (NN / 32), 256, 0, stream>>>(pk, e1, e2, e2m, whF, out);
}